// Round 19
// baseline (350.082 us; speedup 1.0000x reference)
//
#include <hip/hip_runtime.h>

// AttentionLayer: B=16, T=S=C=E=1024, NORM_C=0.5
// out  = (ctx @ w_out^T + b_out + x) * sqrt(.5)   [f32]
// attn = softmax(mask(h @ K))                     [f32]
// R19: R15 phase skeleton + TRIPLE-buffered LDS. Stages target buf (u+2)%3
//      (never read during tiles u/u+1) -> stage-to-read distance 4 phases,
//      VMCNT(9) per phase (forces 3-phase-old loads, ~2800cy cover vs
//      R15's 1200cy). Tail waits (9,6),(3,0) re-derived. BM=256 BN=128,
//      8 waves 4x2, 2 phases/tile, LDS 144KB.

#define SCALE_F 0.70710678118654752440f

constexpr int BB = 16, TT = 1024, SS = 1024, CC = 1024, EE = 1024;

typedef float    f32x4 __attribute__((ext_vector_type(4)));
typedef _Float16 f16x8 __attribute__((ext_vector_type(8)));
typedef _Float16 f16x4 __attribute__((ext_vector_type(4)));

__device__ __forceinline__ void gload_lds16(const _Float16* g, _Float16* l) {
  __builtin_amdgcn_global_load_lds((const __attribute__((address_space(1))) void*)g,
                                   (__attribute__((address_space(3))) void*)l,
                                   16, 0, 0);
}

#define VMCNT(N) asm volatile("s_waitcnt vmcnt(" #N ")" ::: "memory")
#define LGKM(N)  asm volatile("s_waitcnt lgkmcnt(" #N ")" ::: "memory")
#define SBAR()   asm volatile("s_barrier" ::: "memory")
#define DSR(dst, a, off) \
  asm volatile("ds_read_b128 %0, %1 offset:" #off : "=v"(dst) : "v"(a))

// ---------------------------------------------------------------- conversions
__global__ __launch_bounds__(256) void cvt_f16(const float* __restrict__ s,
                                               _Float16* __restrict__ d, long n) {
  long i = ((long)blockIdx.x * 256 + threadIdx.x) * 8;
  if (i >= n) return;
  f32x4 a = *(const f32x4*)(s + i);
  f32x4 b = *(const f32x4*)(s + i + 4);
  f16x8 h;
  h[0]=(_Float16)a[0]; h[1]=(_Float16)a[1]; h[2]=(_Float16)a[2]; h[3]=(_Float16)a[3];
  h[4]=(_Float16)b[0]; h[5]=(_Float16)b[1]; h[6]=(_Float16)b[2]; h[7]=(_Float16)b[3];
  *(f16x8*)(d + i) = h;
}

// two 1M-element weight casts in one launch (y selects src/dst)
__global__ __launch_bounds__(256) void cvt_w(const float* __restrict__ s0,
                                             _Float16* __restrict__ d0,
                                             const float* __restrict__ s1,
                                             _Float16* __restrict__ d1) {
  const float* s = blockIdx.y ? s1 : s0;
  _Float16* d = blockIdx.y ? d1 : d0;
  long i = ((long)blockIdx.x * 256 + threadIdx.x) * 8;
  f32x4 a = *(const f32x4*)(s + i);
  f32x4 b = *(const f32x4*)(s + i + 4);
  f16x8 h;
  h[0]=(_Float16)a[0]; h[1]=(_Float16)a[1]; h[2]=(_Float16)a[2]; h[3]=(_Float16)a[3];
  h[4]=(_Float16)b[0]; h[5]=(_Float16)b[1]; h[6]=(_Float16)b[2]; h[7]=(_Float16)b[3];
  *(f16x8*)(d + i) = h;
}

// [B][R][Cc] f32 -> [B][Cc][R] f16 ; z<BB: keys->keysT, z>=BB: vals->valsT
__global__ __launch_bounds__(256) void transpose_cvt(const float* __restrict__ src0,
                                                     _Float16* __restrict__ dst0,
                                                     const float* __restrict__ src1,
                                                     _Float16* __restrict__ dst1) {
  __shared__ float tile[64][65];
  const int zz = blockIdx.z;
  const int b = zz & (BB - 1);
  const float* src = (zz < BB) ? src0 : src1;
  _Float16* dst = (zz < BB) ? dst0 : dst1;
  const int R = 1024, Cc = 1024;
  const int r0 = blockIdx.y * 64, c0 = blockIdx.x * 64;
  const int t = threadIdx.x;
  const int tr = t >> 4, tc4 = (t & 15) * 4;
  const float* s = src + (size_t)b * R * Cc;
#pragma unroll
  for (int i = 0; i < 4; ++i) {
    f32x4 v = *(const f32x4*)(s + (size_t)(r0 + i * 16 + tr) * Cc + c0 + tc4);
    tile[i * 16 + tr][tc4 + 0] = v[0]; tile[i * 16 + tr][tc4 + 1] = v[1];
    tile[i * 16 + tr][tc4 + 2] = v[2]; tile[i * 16 + tr][tc4 + 3] = v[3];
  }
  __syncthreads();
  _Float16* d = dst + (size_t)b * Cc * R;
#pragma unroll
  for (int j = 0; j < 4; ++j) {
    const int cl = j * 16 + tr;
    f16x4 h;
    h[0] = (_Float16)tile[tc4 + 0][cl]; h[1] = (_Float16)tile[tc4 + 1][cl];
    h[2] = (_Float16)tile[tc4 + 2][cl]; h[3] = (_Float16)tile[tc4 + 3][cl];
    *(f16x4*)(d + (size_t)(c0 + cl) * R + r0 + tc4) = h;
  }
}

// ------------------------------------------------------------------- mask prep
__global__ __launch_bounds__(256) void mask_prep(const unsigned char* __restrict__ mraw,
                                                 float* __restrict__ maskneg,
                                                 float* __restrict__ sscale) {
  const int b = blockIdx.x, t = threadIdx.x;
  __shared__ int bytemode_sh, cnt_sh;
  if (t == 0) { bytemode_sh = 0; cnt_sh = 0; }
  __syncthreads();
  const unsigned int* mu = (const unsigned int*)mraw;
  int local = 0;
  for (int i = t; i < (BB * SS) / 4; i += 256) {
    unsigned int v = mu[i];
    if (v != 0u && v != 1u && v != 0x3f800000u) local = 1;
  }
  if (local) atomicOr(&bytemode_sh, 1);
  __syncthreads();
  const int bytemode = bytemode_sh;
  int cnt = 0;
  for (int s = t; s < SS; s += 256) {
    int m = bytemode ? (mraw[b * SS + s] != 0) : (mu[b * SS + s] != 0u);
    maskneg[b * SS + s] = m ? -__builtin_inff() : 0.0f;
    cnt += m;
  }
#pragma unroll
  for (int o = 32; o; o >>= 1) cnt += __shfl_down(cnt, o);
  if ((t & 63) == 0) atomicAdd(&cnt_sh, cnt);
  __syncthreads();
  if (t == 0) {
    float sv = (float)SS - (float)cnt_sh;
    sscale[b] = sv * rsqrtf(sv);
  }
}

// ---------------------------------------------------------------------- GEMM
// C[M,N] = A[M,K] @ Bmat[N,K]^T ; fp16 K-major, f32 accum.
// BM=256 BN=128 BK=64; 512 thr = 8 waves (wm 0..3 x wn 0..1); wave 64x64,
// acc[4][4]. LDS 144KB: A[3buf][2kh][256r][32k] (32KB/buf) at byte 0;
// B[3buf][2kh][128r][32k] (16KB/buf) at byte 98304. Rows 64B, 4x16B slots;
// slot s of row r holds k-chunk s^(r&3) (2-way free; inverse on stage src).
// Tile u reads buf u%3; phases stage tile u+2 into (u+2)%3 (untouched by
// readers for 2 whole tiles). Per phase (kh): {DSR 8 | stage A-kh(u+2)[2]
// + B-kh(u+2)[1] | SBAR | lgkm0+schedbar | setprio 16 MFMA | wait | SBAR}.
// Ledger (3 loads/phase): VMCNT(9) forces 3-phase-old loads; region staged
// at phase s is first read at s+4 -> forced at s+3 with ~2800cy to land.
// Tail: u==nt-3: (9,6); u==nt-2: (3,0); u==nt-1: none. All verified.
template <int EPI>
__global__ __launch_bounds__(512, 2)
void gemm_p3(const _Float16* __restrict__ A, const _Float16* __restrict__ Bmat,
             long aStride, long bStride, long oStride,
             int M, int N, int K,
             void* __restrict__ outp,
             const float* __restrict__ bias,
             const void* __restrict__ addmat,
             const float* __restrict__ extra) {
  __shared__ __attribute__((aligned(16))) _Float16 smem[73728];  // 144 KB

  const int t = threadIdx.x;
  const int lane = t & 63;
  const int wid = t >> 6;
  const int wm = wid >> 1, wn = wid & 1;
  const int z = blockIdx.z;
  const int lo = lane & 15, hi = lane >> 4;
  const int nt = K >> 6;                     // 16 (>= 4)

  // XCD-aware bijective swizzle (gx*gy % 8 == 0 for all our grids)
  const int gx = gridDim.x;
  const int fblk = blockIdx.x + blockIdx.y * gx;
  const int q = (gx * gridDim.y) >> 3;
  const int wg = (fblk & 7) * q + (fblk >> 3);
  const long rowBase = (long)(wg / gx) * 256;
  const long colBase = (long)(wg % gx) * 128;

  const _Float16* Ag = A + (size_t)z * aStride + rowBase * K;
  const _Float16* Bg = Bmat + (size_t)z * bStride + colBase * K;

  // staging: thread t -> row t>>2 (0..127), slot t&3; src chunk inverse-swz.
  const int strow = t >> 2;
  const int stchunk = (t & 3) ^ (strow & 3);

  f32x4 acc[4][4] = {};

  // stage A-kh of tile U into buf b3 (2 loads); B-kh (1 load)
  auto stgA = [&](int U, int b3, int kh) {
    _Float16* ab = &smem[b3 * 16384 + kh * 8192];
    const size_t ko = (size_t)U * 64 + kh * 32 + stchunk * 8;
    gload_lds16(Ag + (size_t)strow * K + ko, ab + t * 8);
    gload_lds16(Ag + (size_t)(128 + strow) * K + ko, ab + 4096 + t * 8);
  };
  auto stgB = [&](int U, int b3, int kh) {
    _Float16* bb = &smem[49152 + b3 * 8192 + kh * 4096];
    gload_lds16(Bg + (size_t)strow * K + (size_t)U * 64 + kh * 32 + stchunk * 8,
                bb + t * 8);
  };

  // fragment read bases (bytes); kh/buf offsets added per phase
  const int lds0 = (int)(size_t)&smem[0];
  const int slotx = (hi ^ (lo & 3)) << 4;
  const int abase = lds0 + wm * 4096 + lo * 64 + slotx;
  const int bbase = lds0 + 98304 + wn * 4096 + lo * 64 + slotx;

  // prologue: tiles 0 and 1 complete (12 loads); drain once
  stgA(0, 0, 0); stgA(0, 0, 1); stgB(0, 0, 0); stgB(0, 0, 1);
  stgA(1, 1, 0); stgA(1, 1, 1); stgB(1, 1, 0); stgB(1, 1, 1);
  VMCNT(0);
  SBAR();

  int bufR = 0, bufS = 2;
  for (int u = 0; u < nt; ++u) {
    const int aadB = abase + bufR * 32768;
    const int badB = bbase + bufR * 16384;
#pragma unroll
    for (int kh = 0; kh < 2; ++kh) {
      const int aad = aadB + kh * 16384;
      const int bad = badB + kh * 8192;
      f16x8 a_[4], b_[4];
      DSR(a_[0], aad, 0); DSR(a_[1], aad, 1024);
      DSR(a_[2], aad, 2048); DSR(a_[3], aad, 3072);
      DSR(b_[0], bad, 0); DSR(b_[1], bad, 1024);
      DSR(b_[2], bad, 2048); DSR(b_[3], bad, 3072);
      if (u + 2 < nt) { stgA(u + 2, bufS, kh); stgB(u + 2, bufS, kh); }
      SBAR();
      LGKM(0);
      __builtin_amdgcn_sched_barrier(0);
      __builtin_amdgcn_s_setprio(1);
#pragma unroll
      for (int mi = 0; mi < 4; ++mi)
#pragma unroll
        for (int ni = 0; ni < 4; ++ni)
          acc[mi][ni] = __builtin_amdgcn_mfma_f32_16x16x32_f16(
              a_[mi], b_[ni], acc[mi][ni], 0, 0, 0);
      __builtin_amdgcn_s_setprio(0);
      if (u < nt - 3)            { VMCNT(9); }
      else if (u == nt - 3)      { if (kh == 0) { VMCNT(9); } else { VMCNT(6); } }
      else if (u == nt - 2)      { if (kh == 0) { VMCNT(3); } else { VMCNT(0); } }
      SBAR();
    }
    bufR = (bufR == 2) ? 0 : bufR + 1;
    bufS = (bufS == 2) ? 0 : bufS + 1;
  }

  LGKM(0);
  __syncthreads();

  // ---- vectorized epilogue (R16's, verified): per-wave LDS transpose.
  constexpr int EPS = 68;
  const int fr = lane & 15;
  const int fq = (lane >> 4) * 4;
  const int er = lane >> 2;
  const int ec = (lane & 3) * 16;
  const long gc0 = colBase + wn * 64 + ec;
  float* ep = (float*)smem + wid * (16 * EPS);

  f32x4 biasv[4], maskv[4], av[4];
  float sc = 0.f;
  auto load_add = [&](long gr) {
    if constexpr (EPI == 1) {
      const float* am = (const float*)addmat;
#pragma unroll
      for (int i = 0; i < 4; ++i) av[i] = *(const f32x4*)&am[gr * N + gc0 + i * 4];
    } else if constexpr (EPI == 5) {
      const _Float16* am = (const _Float16*)addmat;
      f16x8 h0 = *(const f16x8*)&am[gr * N + gc0];
      f16x8 h1 = *(const f16x8*)&am[gr * N + gc0 + 8];
#pragma unroll
      for (int i = 0; i < 4; ++i) {
        const f16x8& hh = i < 2 ? h0 : h1;
        const int o = (i & 1) * 4;
        av[i][0] = (float)hh[o]; av[i][1] = (float)hh[o + 1];
        av[i][2] = (float)hh[o + 2]; av[i][3] = (float)hh[o + 3];
      }
    }
  };
  if constexpr (EPI == 1 || EPI == 5) {
#pragma unroll
    for (int i = 0; i < 4; ++i) biasv[i] = *(const f32x4*)&bias[gc0 + i * 4];
    load_add(rowBase + wm * 64 + er);
  }
  if constexpr (EPI == 2) {
#pragma unroll
    for (int i = 0; i < 4; ++i)
      maskv[i] = *(const f32x4*)&((const float*)addmat)[(size_t)z * N + gc0 + i * 4];
  }
  if constexpr (EPI == 3) sc = extra[z];

#pragma unroll
  for (int mf = 0; mf < 4; ++mf) {
#pragma unroll
    for (int n = 0; n < 4; ++n)
#pragma unroll
      for (int j = 0; j < 4; ++j)
        ep[(fq + j) * EPS + n * 16 + fr] = acc[mf][n][j];
    __syncthreads();
    const long gr = rowBase + wm * 64 + mf * 16 + er;
    f32x4 r[4];
#pragma unroll
    for (int i = 0; i < 4; ++i) r[i] = *(const f32x4*)&ep[er * EPS + ec + i * 4];
    f32x4 a_cur[4];
    if constexpr (EPI == 1 || EPI == 5) {
#pragma unroll
      for (int i = 0; i < 4; ++i) a_cur[i] = av[i];
      if (mf < 3) load_add(gr + 16);
    }
    if constexpr (EPI == 1) {
      _Float16* o = (_Float16*)outp + gr * N + gc0;
#pragma unroll
      for (int g = 0; g < 2; ++g) {
        f32x4 v0 = (r[2 * g] + biasv[2 * g] + a_cur[2 * g]) * SCALE_F;
        f32x4 v1 = (r[2 * g + 1] + biasv[2 * g + 1] + a_cur[2 * g + 1]) * SCALE_F;
        f16x8 h;
        h[0]=(_Float16)v0[0]; h[1]=(_Float16)v0[1]; h[2]=(_Float16)v0[2]; h[3]=(_Float16)v0[3];
        h[4]=(_Float16)v1[0]; h[5]=(_Float16)v1[1]; h[6]=(_Float16)v1[2]; h[7]=(_Float16)v1[3];
        *(f16x8*)(o + g * 8) = h;
      }
    } else if constexpr (EPI == 2) {
      float* o = (float*)outp + (size_t)z * oStride + gr * N + gc0;
#pragma unroll
      for (int i = 0; i < 4; ++i) *(f32x4*)(o + i * 4) = r[i] + maskv[i];
    } else if constexpr (EPI == 3) {
      _Float16* o = (_Float16*)outp + (size_t)z * oStride + gr * N + gc0;
#pragma unroll
      for (int g = 0; g < 2; ++g) {
        f32x4 v0 = r[2 * g] * sc;
        f32x4 v1 = r[2 * g + 1] * sc;
        f16x8 h;
        h[0]=(_Float16)v0[0]; h[1]=(_Float16)v0[1]; h[2]=(_Float16)v0[2]; h[3]=(_Float16)v0[3];
        h[4]=(_Float16)v1[0]; h[5]=(_Float16)v1[1]; h[6]=(_Float16)v1[2]; h[7]=(_Float16)v1[3];
        *(f16x8*)(o + g * 8) = h;
      }
    } else {
      float* o = (float*)outp + gr * N + gc0;
#pragma unroll
      for (int i = 0; i < 4; ++i)
        *(f32x4*)(o + i * 4) = (r[i] + biasv[i] + a_cur[i]) * SCALE_F;
    }
    __syncthreads();
  }
}

// -------------------------------------------------------------------- softmax
__global__ __launch_bounds__(256) void softmax_k(float* __restrict__ attn,
                                                 _Float16* __restrict__ attn16) {
  const size_t row = blockIdx.x;
  float* p = attn + row * SS;
  const int t = threadIdx.x;
  f32x4 v = *(const f32x4*)(p + t * 4);
  __shared__ float red[8];
  float m = fmaxf(fmaxf(v[0], v[1]), fmaxf(v[2], v[3]));
#pragma unroll
  for (int o = 32; o; o >>= 1) m = fmaxf(m, __shfl_xor(m, o));
  if (!(t & 63)) red[t >> 6] = m;
  __syncthreads();
  m = fmaxf(fmaxf(red[0], red[1]), fmaxf(red[2], red[3]));
  f32x4 e;
  e[0] = __expf(v[0] - m); e[1] = __expf(v[1] - m);
  e[2] = __expf(v[2] - m); e[3] = __expf(v[3] - m);
  float s = e[0] + e[1] + e[2] + e[3];
#pragma unroll
  for (int o = 32; o; o >>= 1) s += __shfl_xor(s, o);
  if (!(t & 63)) red[4 + (t >> 6)] = s;
  __syncthreads();
  s = red[4] + red[5] + red[6] + red[7];
  const float inv = 1.0f / s;
  f32x4 o4; o4[0]=e[0]*inv; o4[1]=e[1]*inv; o4[2]=e[2]*inv; o4[3]=e[3]*inv;
  *(f32x4*)(p + t * 4) = o4;
  f16x4 h; h[0]=(_Float16)o4[0]; h[1]=(_Float16)o4[1];
  h[2]=(_Float16)o4[2]; h[3]=(_Float16)o4[3];
  *(f16x4*)(attn16 + row * SS + t * 4) = h;
}

// -------------------------------------------------------------------- launch
extern "C" void kernel_launch(void* const* d_in, const int* in_sizes, int n_in,
                              void* d_out, int out_size, void* d_ws, size_t ws_size,
                              hipStream_t stream) {
  const float* x     = (const float*)d_in[0];
  const float* te    = (const float*)d_in[1];
  const float* keys  = (const float*)d_in[2];
  const float* vals  = (const float*)d_in[3];
  const void*  mask  = d_in[4];
  const float* w_in  = (const float*)d_in[5];
  const float* b_in  = (const float*)d_in[6];
  const float* w_out = (const float*)d_in[7];
  const float* b_out = (const float*)d_in[8];

  char* ws = (char*)d_ws;
  const size_t MB32 = 33554432;
  _Float16* buf0   = (_Float16*)(ws);              // x16 (lives to the end)
  _Float16* buf1   = (_Float16*)(ws + MB32);       // h16 -> attn16 (in place)
  _Float16* keysT  = (_Float16*)(ws + 2 * MB32);   // keysT -> ctx16 after sm
  _Float16* valsT  = (_Float16*)(ws + 3 * MB32);
  _Float16* win16  = (_Float16*)(ws + 4 * MB32);
  _Float16* wout16 = (_Float16*)(ws + 4 * MB32 + 2097152);
  float*    maskneg= (float*)   (ws + 4 * MB32 + 2 * 2097152);
  float*    sscale = (float*)   (ws + 4 * MB32 + 2 * 2097152 + 65536);

  float* out_main = (float*)d_out;
  float* attn_out = (float*)d_out + (size_t)BB * TT * CC;

  cvt_f16<<<dim3(16777216 / 2048), 256, 0, stream>>>(x, buf0, 16777216);
  cvt_w<<<dim3(1048576 / 2048, 2), 256, 0, stream>>>(w_in, win16, w_out, wout16);
  transpose_cvt<<<dim3(16, 16, 2 * BB), 256, 0, stream>>>(keys, keysT, vals, valsT);
  mask_prep<<<dim3(BB), 256, 0, stream>>>((const unsigned char*)mask, maskneg, sscale);

  // GEMM1: h16 = (x16 @ w_in^T + b_in + te)*s
  gemm_p3<1><<<dim3(EE / 128, (BB * TT) / 256, 1), 512, 0, stream>>>(
      buf0, win16, 0, 0, 0, BB * TT, EE, CC, buf1, b_in, te, nullptr);
  // GEMM2: scores = h16 @ keysT^T + maskneg -> attn region (f32)
  gemm_p3<2><<<dim3(SS / 128, TT / 256, BB), 512, 0, stream>>>(
      buf1, keysT, (long)TT * EE, (long)SS * EE, (long)TT * SS,
      TT, SS, EE, attn_out, nullptr, maskneg, nullptr);
  // softmax in-place + f16 copy into buf1
  softmax_k<<<dim3(BB * TT), 256, 0, stream>>>(attn_out, buf1);
  // GEMM3: ctx16 = (attn16 @ valsT^T)*sqrt(s_b) -> keysT region
  gemm_p3<3><<<dim3(EE / 128, TT / 256, BB), 512, 0, stream>>>(
      buf1, valsT, (long)TT * SS, (long)EE * SS, (long)TT * EE,
      TT, EE, SS, keysT, nullptr, nullptr, sscale);
  // GEMM4: out = (ctx16 @ w_out^T + b_out + x16)*s  (f16 residual)
  gemm_p3<5><<<dim3(CC / 128, (BB * TT) / 256, 1), 512, 0, stream>>>(
      keysT, wout16, 0, 0, 0, BB * TT, CC, EE, out_main, b_out, buf0, nullptr);
}

// Round 20
// 304.424 us; speedup vs baseline: 1.1500x; 1.1500x over previous
//
#include <hip/hip_runtime.h>

// AttentionLayer: B=16, T=S=C=E=1024, NORM_C=0.5
// out  = (ctx @ w_out^T + b_out + x) * sqrt(.5)   [f32]
// attn = softmax(mask(h @ K))                     [f32]
// R20 = R18 (verified best, 305.2us): fp16 MFMA pipeline, 256x256 8-phase
//      counted-vmcnt GEMM with B-register reuse, merged prepass, f16
//      residual. R19's triple-buffer regressed (bank conflicts + B re-fetch);
//      reverted.

#define SCALE_F 0.70710678118654752440f

constexpr int BB = 16, TT = 1024, SS = 1024, CC = 1024, EE = 1024;

typedef float    f32x4 __attribute__((ext_vector_type(4)));
typedef _Float16 f16x8 __attribute__((ext_vector_type(8)));
typedef _Float16 f16x4 __attribute__((ext_vector_type(4)));

__device__ __forceinline__ void gload_lds16(const _Float16* g, _Float16* l) {
  __builtin_amdgcn_global_load_lds((const __attribute__((address_space(1))) void*)g,
                                   (__attribute__((address_space(3))) void*)l,
                                   16, 0, 0);
}

#define VMCNT(N) asm volatile("s_waitcnt vmcnt(" #N ")" ::: "memory")
#define LGKM(N)  asm volatile("s_waitcnt lgkmcnt(" #N ")" ::: "memory")
#define SBAR()   asm volatile("s_barrier" ::: "memory")
#define DSR(dst, a, off) \
  asm volatile("ds_read_b128 %0, %1 offset:" #off : "=v"(dst) : "v"(a))

// ---------------------------------------------------------------- conversions
__global__ __launch_bounds__(256) void cvt_f16(const float* __restrict__ s,
                                               _Float16* __restrict__ d, long n) {
  long i = ((long)blockIdx.x * 256 + threadIdx.x) * 8;
  if (i >= n) return;
  f32x4 a = *(const f32x4*)(s + i);
  f32x4 b = *(const f32x4*)(s + i + 4);
  f16x8 h;
  h[0]=(_Float16)a[0]; h[1]=(_Float16)a[1]; h[2]=(_Float16)a[2]; h[3]=(_Float16)a[3];
  h[4]=(_Float16)b[0]; h[5]=(_Float16)b[1]; h[6]=(_Float16)b[2]; h[7]=(_Float16)b[3];
  *(f16x8*)(d + i) = h;
}

// two 1M-element weight casts in one launch (y selects src/dst)
__global__ __launch_bounds__(256) void cvt_w(const float* __restrict__ s0,
                                             _Float16* __restrict__ d0,
                                             const float* __restrict__ s1,
                                             _Float16* __restrict__ d1) {
  const float* s = blockIdx.y ? s1 : s0;
  _Float16* d = blockIdx.y ? d1 : d0;
  long i = ((long)blockIdx.x * 256 + threadIdx.x) * 8;
  f32x4 a = *(const f32x4*)(s + i);
  f32x4 b = *(const f32x4*)(s + i + 4);
  f16x8 h;
  h[0]=(_Float16)a[0]; h[1]=(_Float16)a[1]; h[2]=(_Float16)a[2]; h[3]=(_Float16)a[3];
  h[4]=(_Float16)b[0]; h[5]=(_Float16)b[1]; h[6]=(_Float16)b[2]; h[7]=(_Float16)b[3];
  *(f16x8*)(d + i) = h;
}

// [B][R][Cc] f32 -> [B][Cc][R] f16 ; z<BB: keys->keysT, z>=BB: vals->valsT
__global__ __launch_bounds__(256) void transpose_cvt(const float* __restrict__ src0,
                                                     _Float16* __restrict__ dst0,
                                                     const float* __restrict__ src1,
                                                     _Float16* __restrict__ dst1) {
  __shared__ float tile[64][65];
  const int zz = blockIdx.z;
  const int b = zz & (BB - 1);
  const float* src = (zz < BB) ? src0 : src1;
  _Float16* dst = (zz < BB) ? dst0 : dst1;
  const int R = 1024, Cc = 1024;
  const int r0 = blockIdx.y * 64, c0 = blockIdx.x * 64;
  const int t = threadIdx.x;
  const int tr = t >> 4, tc4 = (t & 15) * 4;
  const float* s = src + (size_t)b * R * Cc;
#pragma unroll
  for (int i = 0; i < 4; ++i) {
    f32x4 v = *(const f32x4*)(s + (size_t)(r0 + i * 16 + tr) * Cc + c0 + tc4);
    tile[i * 16 + tr][tc4 + 0] = v[0]; tile[i * 16 + tr][tc4 + 1] = v[1];
    tile[i * 16 + tr][tc4 + 2] = v[2]; tile[i * 16 + tr][tc4 + 3] = v[3];
  }
  __syncthreads();
  _Float16* d = dst + (size_t)b * Cc * R;
#pragma unroll
  for (int j = 0; j < 4; ++j) {
    const int cl = j * 16 + tr;
    f16x4 h;
    h[0] = (_Float16)tile[tc4 + 0][cl]; h[1] = (_Float16)tile[tc4 + 1][cl];
    h[2] = (_Float16)tile[tc4 + 2][cl]; h[3] = (_Float16)tile[tc4 + 3][cl];
    *(f16x4*)(d + (size_t)(c0 + cl) * R + r0 + tc4) = h;
  }
}

// ------------------------------------------------------------------- mask prep
__global__ __launch_bounds__(256) void mask_prep(const unsigned char* __restrict__ mraw,
                                                 float* __restrict__ maskneg,
                                                 float* __restrict__ sscale) {
  const int b = blockIdx.x, t = threadIdx.x;
  __shared__ int bytemode_sh, cnt_sh;
  if (t == 0) { bytemode_sh = 0; cnt_sh = 0; }
  __syncthreads();
  const unsigned int* mu = (const unsigned int*)mraw;
  int local = 0;
  for (int i = t; i < (BB * SS) / 4; i += 256) {
    unsigned int v = mu[i];
    if (v != 0u && v != 1u && v != 0x3f800000u) local = 1;
  }
  if (local) atomicOr(&bytemode_sh, 1);
  __syncthreads();
  const int bytemode = bytemode_sh;
  int cnt = 0;
  for (int s = t; s < SS; s += 256) {
    int m = bytemode ? (mraw[b * SS + s] != 0) : (mu[b * SS + s] != 0u);
    maskneg[b * SS + s] = m ? -__builtin_inff() : 0.0f;
    cnt += m;
  }
#pragma unroll
  for (int o = 32; o; o >>= 1) cnt += __shfl_down(cnt, o);
  if ((t & 63) == 0) atomicAdd(&cnt_sh, cnt);
  __syncthreads();
  if (t == 0) {
    float sv = (float)SS - (float)cnt_sh;
    sscale[b] = sv * rsqrtf(sv);
  }
}

// ---------------------------------------------------------------------- GEMM
// (R15/R18 structure, verified best) C[M,N] = A[M,K] @ Bmat[N,K]^T.
// BM=BN=256, BK=64; 512 thr = 8 waves (wm 0..1 x wn 0..3); wave 128x64,
// acc[8][4]. LDS 128KB; slot s of row r holds k-chunk s ^ ((r>>1)&3).
// 8 phases / 2 tiles; PHB reads A+B (latch bk[KS]); PHA reads A only.
// Every phase: stage one 2-load region | SBAR | lgkm0 | 16 MFMA | vmcnt(4)
// | SBAR. Verified ledger (R11/R15).
template <int EPI>
__global__ __launch_bounds__(512, 2)
void gemm8p(const _Float16* __restrict__ A, const _Float16* __restrict__ Bmat,
            long aStride, long bStride, long oStride,
            int M, int N, int K,
            void* __restrict__ outp,
            const float* __restrict__ bias,
            const void* __restrict__ addmat,
            const float* __restrict__ extra) {
  __shared__ __attribute__((aligned(16))) _Float16 smem[65536];  // 128 KB

  const int t = threadIdx.x;
  const int lane = t & 63;
  const int wid = t >> 6;
  const int wm = wid >> 2, wn = wid & 3;
  const int z = blockIdx.z;
  const int lo = lane & 15, hi = lane >> 4;
  const int nt = K >> 6;                     // 16 (even, >=4)

  // XCD-aware bijective swizzle (gx*gy % 8 == 0 for all our grids)
  const int gx = gridDim.x;
  const int fblk = blockIdx.x + blockIdx.y * gx;
  const int q = (gx * gridDim.y) >> 3;
  const int wg = (fblk & 7) * q + (fblk >> 3);
  const long rowBase = (long)(wg / gx) * 256;
  const long colBase = (long)(wg % gx) * 256;

  const _Float16* Ag = A + (size_t)z * aStride + rowBase * K;
  const _Float16* Bg = Bmat + (size_t)z * bStride + colBase * K;

  const int strow = t >> 2;                       // row within 128-group
  const int stchunk = (t & 3) ^ ((t >> 3) & 3);   // inverse-swizzled k-chunk

  f32x4 acc[8][4] = {};
  f16x8 bk[2][4];                                 // B fragments latched per ks

#define STG(T, Q)                                                              \
  if ((T) < nt) {                                                              \
    const int op_ = (Q) & 1, kh_ = (Q) >> 1;                                   \
    const _Float16* g_ = op_ ? Bg : Ag;                                        \
    _Float16* db_ = &smem[op_ * 32768 + ((T) & 1) * 16384 + kh_ * 8192];       \
    const size_t ko_ = (size_t)(T) * 64 + kh_ * 32 + stchunk * 8;              \
    gload_lds16(g_ + (size_t)strow * K + ko_, db_ + t * 8);                    \
    gload_lds16(g_ + (size_t)(128 + strow) * K + ko_, db_ + 4096 + t * 8);     \
  }

  const int lds0 = (int)(size_t)&smem[0];
  const int slotx = (hi ^ ((lo >> 1) & 3)) << 4;
  const int abase = lds0 + wm * 8192 + lo * 64 + slotx;
  const int bbase = lds0 + 65536 + wn * 4096 + lo * 64 + slotx;

#define PHB(KS, U, TS, QQ)                                                     \
  {                                                                            \
    const int aad = abase + ((U) & 1) * 32768 + (KS) * 16384;                  \
    const int bad = bbase + ((U) & 1) * 32768 + (KS) * 16384;                  \
    f16x8 a_[4];                                                               \
    DSR(a_[0], aad, 0); DSR(a_[1], aad, 1024);                                 \
    DSR(a_[2], aad, 2048); DSR(a_[3], aad, 3072);                              \
    DSR(bk[KS][0], bad, 0); DSR(bk[KS][1], bad, 1024);                         \
    DSR(bk[KS][2], bad, 2048); DSR(bk[KS][3], bad, 3072);                      \
    STG(TS, QQ)                                                                \
    SBAR();                                                                    \
    LGKM(0);                                                                   \
    __builtin_amdgcn_sched_barrier(0);                                         \
    __builtin_amdgcn_s_setprio(1);                                             \
    _Pragma("unroll") for (int mi_ = 0; mi_ < 4; ++mi_)                        \
      _Pragma("unroll") for (int ni_ = 0; ni_ < 4; ++ni_)                      \
        acc[mi_][ni_] = __builtin_amdgcn_mfma_f32_16x16x32_f16(                \
            a_[mi_], bk[KS][ni_], acc[mi_][ni_], 0, 0, 0);                     \
    __builtin_amdgcn_s_setprio(0);                                             \
    VMCNT(4);                                                                  \
    SBAR();                                                                    \
  }

#define PHA(KS, U, TS, QQ)                                                     \
  {                                                                            \
    const int aad = abase + ((U) & 1) * 32768 + (KS) * 16384 + 4096;           \
    f16x8 a_[4];                                                               \
    DSR(a_[0], aad, 0); DSR(a_[1], aad, 1024);                                 \
    DSR(a_[2], aad, 2048); DSR(a_[3], aad, 3072);                              \
    STG(TS, QQ)                                                                \
    SBAR();                                                                    \
    LGKM(0);                                                                   \
    __builtin_amdgcn_sched_barrier(0);                                         \
    __builtin_amdgcn_s_setprio(1);                                             \
    _Pragma("unroll") for (int mi_ = 0; mi_ < 4; ++mi_)                        \
      _Pragma("unroll") for (int ni_ = 0; ni_ < 4; ++ni_)                      \
        acc[4 + mi_][ni_] = __builtin_amdgcn_mfma_f32_16x16x32_f16(            \
            a_[mi_], bk[KS][ni_], acc[4 + mi_][ni_], 0, 0, 0);                 \
    __builtin_amdgcn_s_setprio(0);                                             \
    VMCNT(4);                                                                  \
    SBAR();                                                                    \
  }

  // prologue: tile 0 (all regions) + A-kh0 of tile 1
  STG(0, 0) STG(0, 1) STG(0, 2) STG(0, 3) STG(1, 0)
  VMCNT(0);
  SBAR();

  for (int I = 0; I < (nt >> 1); ++I) {
    const int u = 2 * I;
    PHB(0, u,     u + 1, 1)
    PHB(1, u,     u + 1, 2)
    PHA(0, u,     u + 1, 3)
    PHA(1, u,     u + 2, 0)
    PHB(0, u + 1, u + 2, 1)
    PHB(1, u + 1, u + 2, 2)
    PHA(0, u + 1, u + 2, 3)
    PHA(1, u + 1, u + 3, 0)
  }

  VMCNT(0);
  LGKM(0);
  __syncthreads();

  // ---- vectorized epilogue: per-wave LDS transpose (barriers REQUIRED:
  // cross-lane RAW is only ordered by them — R17 lesson).
  constexpr int EPS = 68;
  const int fr = lane & 15;
  const int fq = (lane >> 4) * 4;
  const int er = lane >> 2;
  const int ec = (lane & 3) * 16;
  const long gc0 = colBase + wn * 64 + ec;
  float* ep = (float*)smem + wid * (16 * EPS);

  f32x4 biasv[4], maskv[4], av[4];
  float sc = 0.f;
  auto load_add = [&](long gr) {
    if constexpr (EPI == 1) {
      const float* am = (const float*)addmat;
#pragma unroll
      for (int i = 0; i < 4; ++i) av[i] = *(const f32x4*)&am[gr * N + gc0 + i * 4];
    } else if constexpr (EPI == 5) {
      const _Float16* am = (const _Float16*)addmat;
      f16x8 h0 = *(const f16x8*)&am[gr * N + gc0];
      f16x8 h1 = *(const f16x8*)&am[gr * N + gc0 + 8];
#pragma unroll
      for (int i = 0; i < 4; ++i) {
        const f16x8& hh = i < 2 ? h0 : h1;
        const int o = (i & 1) * 4;
        av[i][0] = (float)hh[o]; av[i][1] = (float)hh[o + 1];
        av[i][2] = (float)hh[o + 2]; av[i][3] = (float)hh[o + 3];
      }
    }
  };
  if constexpr (EPI == 1 || EPI == 5) {
#pragma unroll
    for (int i = 0; i < 4; ++i) biasv[i] = *(const f32x4*)&bias[gc0 + i * 4];
    load_add(rowBase + wm * 128 + er);
  }
  if constexpr (EPI == 2) {
#pragma unroll
    for (int i = 0; i < 4; ++i)
      maskv[i] = *(const f32x4*)&((const float*)addmat)[(size_t)z * N + gc0 + i * 4];
  }
  if constexpr (EPI == 3) sc = extra[z];

#pragma unroll
  for (int mf = 0; mf < 8; ++mf) {
#pragma unroll
    for (int n = 0; n < 4; ++n)
#pragma unroll
      for (int j = 0; j < 4; ++j)
        ep[(fq + j) * EPS + n * 16 + fr] = acc[mf][n][j];
    __syncthreads();
    const long gr = rowBase + wm * 128 + mf * 16 + er;
    f32x4 r[4];
#pragma unroll
    for (int i = 0; i < 4; ++i) r[i] = *(const f32x4*)&ep[er * EPS + ec + i * 4];
    f32x4 a_cur[4];
    if constexpr (EPI == 1 || EPI == 5) {
#pragma unroll
      for (int i = 0; i < 4; ++i) a_cur[i] = av[i];
      if (mf < 7) load_add(gr + 16);
    }
    if constexpr (EPI == 1) {
      _Float16* o = (_Float16*)outp + gr * N + gc0;
#pragma unroll
      for (int g = 0; g < 2; ++g) {
        f32x4 v0 = (r[2 * g] + biasv[2 * g] + a_cur[2 * g]) * SCALE_F;
        f32x4 v1 = (r[2 * g + 1] + biasv[2 * g + 1] + a_cur[2 * g + 1]) * SCALE_F;
        f16x8 h;
        h[0]=(_Float16)v0[0]; h[1]=(_Float16)v0[1]; h[2]=(_Float16)v0[2]; h[3]=(_Float16)v0[3];
        h[4]=(_Float16)v1[0]; h[5]=(_Float16)v1[1]; h[6]=(_Float16)v1[2]; h[7]=(_Float16)v1[3];
        *(f16x8*)(o + g * 8) = h;
      }
    } else if constexpr (EPI == 2) {
      float* o = (float*)outp + (size_t)z * oStride + gr * N + gc0;
#pragma unroll
      for (int i = 0; i < 4; ++i) *(f32x4*)(o + i * 4) = r[i] + maskv[i];
    } else if constexpr (EPI == 3) {
      _Float16* o = (_Float16*)outp + (size_t)z * oStride + gr * N + gc0;
#pragma unroll
      for (int g = 0; g < 2; ++g) {
        f32x4 v0 = r[2 * g] * sc;
        f32x4 v1 = r[2 * g + 1] * sc;
        f16x8 h;
        h[0]=(_Float16)v0[0]; h[1]=(_Float16)v0[1]; h[2]=(_Float16)v0[2]; h[3]=(_Float16)v0[3];
        h[4]=(_Float16)v1[0]; h[5]=(_Float16)v1[1]; h[6]=(_Float16)v1[2]; h[7]=(_Float16)v1[3];
        *(f16x8*)(o + g * 8) = h;
      }
    } else {
      float* o = (float*)outp + gr * N + gc0;
#pragma unroll
      for (int i = 0; i < 4; ++i)
        *(f32x4*)(o + i * 4) = (r[i] + biasv[i] + a_cur[i]) * SCALE_F;
    }
    __syncthreads();
  }
}

// -------------------------------------------------------------------- softmax
__global__ __launch_bounds__(256) void softmax_k(float* __restrict__ attn,
                                                 _Float16* __restrict__ attn16) {
  const size_t row = blockIdx.x;
  float* p = attn + row * SS;
  const int t = threadIdx.x;
  f32x4 v = *(const f32x4*)(p + t * 4);
  __shared__ float red[8];
  float m = fmaxf(fmaxf(v[0], v[1]), fmaxf(v[2], v[3]));
#pragma unroll
  for (int o = 32; o; o >>= 1) m = fmaxf(m, __shfl_xor(m, o));
  if (!(t & 63)) red[t >> 6] = m;
  __syncthreads();
  m = fmaxf(fmaxf(red[0], red[1]), fmaxf(red[2], red[3]));
  f32x4 e;
  e[0] = __expf(v[0] - m); e[1] = __expf(v[1] - m);
  e[2] = __expf(v[2] - m); e[3] = __expf(v[3] - m);
  float s = e[0] + e[1] + e[2] + e[3];
#pragma unroll
  for (int o = 32; o; o >>= 1) s += __shfl_xor(s, o);
  if (!(t & 63)) red[4 + (t >> 6)] = s;
  __syncthreads();
  s = red[4] + red[5] + red[6] + red[7];
  const float inv = 1.0f / s;
  f32x4 o4; o4[0]=e[0]*inv; o4[1]=e[1]*inv; o4[2]=e[2]*inv; o4[3]=e[3]*inv;
  *(f32x4*)(p + t * 4) = o4;
  f16x4 h; h[0]=(_Float16)o4[0]; h[1]=(_Float16)o4[1];
  h[2]=(_Float16)o4[2]; h[3]=(_Float16)o4[3];
  *(f16x4*)(attn16 + row * SS + t * 4) = h;
}

// -------------------------------------------------------------------- launch
extern "C" void kernel_launch(void* const* d_in, const int* in_sizes, int n_in,
                              void* d_out, int out_size, void* d_ws, size_t ws_size,
                              hipStream_t stream) {
  const float* x     = (const float*)d_in[0];
  const float* te    = (const float*)d_in[1];
  const float* keys  = (const float*)d_in[2];
  const float* vals  = (const float*)d_in[3];
  const void*  mask  = d_in[4];
  const float* w_in  = (const float*)d_in[5];
  const float* b_in  = (const float*)d_in[6];
  const float* w_out = (const float*)d_in[7];
  const float* b_out = (const float*)d_in[8];

  char* ws = (char*)d_ws;
  const size_t MB32 = 33554432;
  _Float16* buf0   = (_Float16*)(ws);              // x16 (lives to the end)
  _Float16* buf1   = (_Float16*)(ws + MB32);       // h16 -> attn16 (in place)
  _Float16* keysT  = (_Float16*)(ws + 2 * MB32);   // keysT -> ctx16 after sm
  _Float16* valsT  = (_Float16*)(ws + 3 * MB32);
  _Float16* win16  = (_Float16*)(ws + 4 * MB32);
  _Float16* wout16 = (_Float16*)(ws + 4 * MB32 + 2097152);
  float*    maskneg= (float*)   (ws + 4 * MB32 + 2 * 2097152);
  float*    sscale = (float*)   (ws + 4 * MB32 + 2 * 2097152 + 65536);

  float* out_main = (float*)d_out;
  float* attn_out = (float*)d_out + (size_t)BB * TT * CC;

  cvt_f16<<<dim3(16777216 / 2048), 256, 0, stream>>>(x, buf0, 16777216);
  cvt_w<<<dim3(1048576 / 2048, 2), 256, 0, stream>>>(w_in, win16, w_out, wout16);
  transpose_cvt<<<dim3(16, 16, 2 * BB), 256, 0, stream>>>(keys, keysT, vals, valsT);
  mask_prep<<<dim3(BB), 256, 0, stream>>>((const unsigned char*)mask, maskneg, sscale);

  // GEMM1: h16 = (x16 @ w_in^T + b_in + te)*s
  gemm8p<1><<<dim3(EE / 256, (BB * TT) / 256, 1), 512, 0, stream>>>(
      buf0, win16, 0, 0, 0, BB * TT, EE, CC, buf1, b_in, te, nullptr);
  // GEMM2: scores = h16 @ keysT^T + maskneg -> attn region (f32)
  gemm8p<2><<<dim3(SS / 256, TT / 256, BB), 512, 0, stream>>>(
      buf1, keysT, (long)TT * EE, (long)SS * EE, (long)TT * SS,
      TT, SS, EE, attn_out, nullptr, maskneg, nullptr);
  // softmax in-place + f16 copy into buf1
  softmax_k<<<dim3(BB * TT), 256, 0, stream>>>(attn_out, buf1);
  // GEMM3: ctx16 = (attn16 @ valsT^T)*sqrt(s_b) -> keysT region
  gemm8p<3><<<dim3(EE / 256, TT / 256, BB), 512, 0, stream>>>(
      buf1, valsT, (long)TT * SS, (long)EE * SS, (long)TT * EE,
      TT, EE, SS, keysT, nullptr, nullptr, sscale);
  // GEMM4: out = (ctx16 @ w_out^T + b_out + x16)*s  (f16 residual)
  gemm8p<5><<<dim3(CC / 256, (BB * TT) / 256, 1), 512, 0, stream>>>(
      keysT, wout16, 0, 0, 0, BB * TT, CC, EE, out_main, b_out, buf0, nullptr);
}